// Round 9
// baseline (173.936 us; speedup 1.0000x reference)
//
#include <hip/hip_runtime.h>
#include <math.h>

#define FEAT 4096
#define BATCH 4096

// Native vector type: __builtin_nontemporal_load requires int/float/ptr or a
// VECTOR of such — HIP_vector_type<float,4> (a struct) is rejected (round 4).
typedef float nt_float4 __attribute__((ext_vector_type(4)));

// Kernel 1: one block per row (round-0 shape — best measured: 20 waves/CU).
//
// Rounds 0-3 established: dur is invariant (70.6 µs) under register ILP,
// async-LDS MLP, rows/block, and sched fences. Counters show hbm_bytes is
// EXACTLY half of the 201.6 MB read and total BW is EXACTLY 2x HBM BW every
// round => the L3-miss stream gates (pseudo-random ~50% line residue left by
// the harness's restore thrashing the 256 MiB L3; scattered 128B misses cap
// HBM at ~1.43 TB/s row-miss rate), L3 hits ride hidden.
//
// Round 5 verified: nontemporal loads (no-allocate cache policy) turn the
// read into sequential HBM streams — row_dist dropped from 70.6 µs to below
// the top-5 cutoff (<=41 µs vs the 201.6 MB / 6.5 TB/s ~= 31 µs floor);
// total 192.5 -> 173.8 µs. The remaining visible dispatches are the
// harness's own restore fills (~123 µs at 82% HBM peak) — untouchable.
//
// Rounds 7/8: last-block-done fusion (hipMemsetAsync + device ticket) crashed
// the container twice on identical source while THIS source runs clean —
// fusion pattern rejected by the harness; do not reattempt.
//
// Bit-exactness: nt loads return identical bits; per-row op order identical
// to the absmax=0.0 kernel.
__global__ __launch_bounds__(256) void row_dist_kernel(
    const float* __restrict__ o1, const float* __restrict__ o2,
    const float* __restrict__ o3, float* __restrict__ row_out)
{
    const int row = blockIdx.x;
    const int tid = threadIdx.x;
    const nt_float4* p1 = (const nt_float4*)(o1 + (size_t)row * FEAT);
    const nt_float4* p2 = (const nt_float4*)(o2 + (size_t)row * FEAT);
    const nt_float4* p3 = (const nt_float4*)(o3 + (size_t)row * FEAT);

    float s13 = 0.0f, s12 = 0.0f;
    #pragma unroll
    for (int k = 0; k < 4; ++k) {
        const int idx = tid + k * 256;
        const nt_float4 a = __builtin_nontemporal_load(&p1[idx]);
        const nt_float4 b = __builtin_nontemporal_load(&p2[idx]);
        const nt_float4 c = __builtin_nontemporal_load(&p3[idx]);
        float d;
        d = a.x - c.x; s13 = fmaf(d, d, s13);
        d = a.y - c.y; s13 = fmaf(d, d, s13);
        d = a.z - c.z; s13 = fmaf(d, d, s13);
        d = a.w - c.w; s13 = fmaf(d, d, s13);
        d = a.x - b.x; s12 = fmaf(d, d, s12);
        d = a.y - b.y; s12 = fmaf(d, d, s12);
        d = a.z - b.z; s12 = fmaf(d, d, s12);
        d = a.w - b.w; s12 = fmaf(d, d, s12);
    }

    // wave(64)-level butterfly reduce
    #pragma unroll
    for (int off = 32; off > 0; off >>= 1) {
        s13 += __shfl_down(s13, off, 64);
        s12 += __shfl_down(s12, off, 64);
    }

    __shared__ float ls13[4];
    __shared__ float ls12[4];
    const int wave = tid >> 6;
    const int lane = tid & 63;
    if (lane == 0) { ls13[wave] = s13; ls12[wave] = s12; }
    __syncthreads();
    if (tid == 0) {
        const float t13 = ls13[0] + ls13[1] + ls13[2] + ls13[3];
        const float t12 = ls12[0] + ls12[1] + ls12[2] + ls12[3];
        const float compare = 2.0f - sqrtf(t13) + sqrtf(t12);
        row_out[row] = fmaxf(compare, 0.0f);
    }
}

// Kernel 2: reduce the BATCH row values, scale by BATCH (broadcast-sum semantics).
// UNCHANGED: current summation order gives absmax == 0.0 vs the JAX reference.
__global__ __launch_bounds__(1024) void final_reduce_kernel(
    const float* __restrict__ row_vals, float* __restrict__ out)
{
    const int tid = threadIdx.x;
    float s = 0.0f;
    #pragma unroll
    for (int k = 0; k < BATCH / 1024; ++k) s += row_vals[tid + k * 1024];

    #pragma unroll
    for (int off = 32; off > 0; off >>= 1) s += __shfl_down(s, off, 64);

    __shared__ float ls[16];
    const int wave = tid >> 6;
    const int lane = tid & 63;
    if (lane == 0) ls[wave] = s;
    __syncthreads();
    if (tid == 0) {
        float t = 0.0f;
        #pragma unroll
        for (int i = 0; i < 16; ++i) t += ls[i];
        out[0] = t * (float)BATCH;
    }
}

extern "C" void kernel_launch(void* const* d_in, const int* in_sizes, int n_in,
                              void* d_out, int out_size, void* d_ws, size_t ws_size,
                              hipStream_t stream) {
    const float* o1 = (const float*)d_in[0];
    const float* o2 = (const float*)d_in[1];
    const float* o3 = (const float*)d_in[2];
    float* row_ws = (float*)d_ws;          // BATCH floats of scratch
    float* out = (float*)d_out;            // single fp32 scalar

    row_dist_kernel<<<BATCH, 256, 0, stream>>>(o1, o2, o3, row_ws);
    final_reduce_kernel<<<1, 1024, 0, stream>>>(row_ws, out);
}